// Round 8
// baseline (4186.945 us; speedup 1.0000x reference)
//
#include <hip/hip_runtime.h>
#include <stdint.h>

// GP posterior via batched CG. Khat bf16 (128 MB); matvec = 4-phase counted-vmcnt
// MFMA GEMM (~1.4 PF). CG dot-products fused into the gemm epilogue via
// coalesced LDS tile staging (no scattered global reads - r6's failure mode).
// Per iter: gemm(+dots) -> cg_scal (tiny) -> cg_upd (streaming).

#define N_TRAIN 8192
#define N_TEST  4096
#define DIM     16
#define KDIM    8192
#define CG_ITERS 5
#define NT      (KDIM / 64)   // 128 K-tiles

using f32x4  = __attribute__((ext_vector_type(4))) float;
using bf16x8 = __attribute__((ext_vector_type(8))) short;

static __device__ __forceinline__ unsigned short f2bf(float f) {
  unsigned u = __float_as_uint(f);
  u = (u + 0x7FFFu + ((u >> 16) & 1u)) >> 16;   // RNE
  return (unsigned short)u;
}
static __device__ __forceinline__ float bf2f(unsigned short h) {
  return __uint_as_float(((unsigned)h) << 16);
}
static __device__ __forceinline__ float rnd_bf(float f) { return bf2f(f2bf(f)); }

__device__ __forceinline__ void gl_lds16(const void* g, void* l) {
  __builtin_amdgcn_global_load_lds(
      (const __attribute__((address_space(1))) unsigned int*)g,
      (__attribute__((address_space(3))) unsigned int*)l, 16, 0, 0);
}

// ---- prep: rows scaled by 1/lengthscale + squared norms ----
__global__ void prep_kernel(const float* __restrict__ tx, const float* __restrict__ xx,
                            const float* __restrict__ ls,
                            float* __restrict__ As, float* __restrict__ an,
                            float* __restrict__ Bs, float* __restrict__ bn) {
  int i = blockIdx.x * 256 + threadIdx.x;
  if (i < N_TRAIN) {
    float s = 0.f;
    #pragma unroll
    for (int d = 0; d < DIM; ++d) {
      float v = tx[(size_t)i * DIM + d] / ls[d];
      As[(size_t)i * DIM + d] = v; s += v * v;
    }
    an[i] = s;
  } else if (i < N_TRAIN + N_TEST) {
    int j = i - N_TRAIN;
    float s = 0.f;
    #pragma unroll
    for (int d = 0; d < DIM; ++d) {
      float v = xx[(size_t)j * DIM + d] / ls[d];
      Bs[(size_t)j * DIM + d] = v; s += v * v;
    }
    bn[j] = s;
  }
}

// ---- kernel-matrix builder: 2 cols/thread, rows in 2-row chunks ----
template <bool NOISE>
__global__ __launch_bounds__(256) void build_kernel(
    const float* __restrict__ RI, const float* __restrict__ nI,
    const float* __restrict__ RJ, const float* __restrict__ nJ,
    unsigned short* __restrict__ O1,
    const float* __restrict__ osc, const float* __restrict__ noi)
{
  __shared__ float aI[128 * DIM];
  __shared__ float sI[128];
  int t = threadIdx.x;
  int j0 = blockIdx.x * 512, i0 = blockIdx.y * 128;
  for (int e = t; e < 128 * DIM; e += 256) aI[e] = RI[(size_t)i0 * DIM + e];
  if (t < 128) sI[t] = nI[i0 + t];
  __syncthreads();

  int ja = j0 + t, jb = ja + 256;
  f32x4 aj0[4], aj1[4];
  const f32x4* RJa = (const f32x4*)(RJ + (size_t)ja * DIM);
  const f32x4* RJb = (const f32x4*)(RJ + (size_t)jb * DIM);
  #pragma unroll
  for (int q = 0; q < 4; ++q) { aj0[q] = RJa[q]; aj1[q] = RJb[q]; }
  float nja = nJ[ja], njb = nJ[jb];
  float s = osc[0], sn = noi[0];

  for (int ic = 0; ic < 128; ic += 2) {
    f32x4 rv[2][4];
    #pragma unroll
    for (int r = 0; r < 2; ++r)
      #pragma unroll
      for (int q = 0; q < 4; ++q)
        rv[r][q] = *(const f32x4*)&aI[(ic + r) * DIM + q * 4];
    #pragma unroll
    for (int r = 0; r < 2; ++r) {
      int i = ic + r;
      float d0 = 0.f, d1 = 0.f;
      #pragma unroll
      for (int q = 0; q < 4; ++q) {
        f32x4 ai = rv[r][q];
        d0 += ai[0]*aj0[q][0] + ai[1]*aj0[q][1] + ai[2]*aj0[q][2] + ai[3]*aj0[q][3];
        d1 += ai[0]*aj1[q][0] + ai[1]*aj1[q][1] + ai[2]*aj1[q][2] + ai[3]*aj1[q][3];
      }
      float d2a = fmaxf(sI[i] + nja - 2.f * d0, 0.f);
      float d2b = fmaxf(sI[i] + njb - 2.f * d1, 0.f);
      float va = s * __expf(-0.5f * d2a);
      float vb = s * __expf(-0.5f * d2b);
      if (NOISE && (i0 + i == ja)) va += sn;
      if (NOISE && (i0 + i == jb)) vb += sn;
      size_t rowb = (size_t)(i0 + i) * KDIM;
      O1[rowb + ja] = f2bf(va); O1[rowb + jb] = f2bf(vb);
    }
  }
}

// =====================  pipelined MFMA GEMM + LDS-staged dot epilogue  ==========
// MODE 0 (it0, p==r==b): store Q; dots {pq,qq,yq,bb,yb} -> slots {0,2,3,4,5}
// MODE 1 (mid):          store Q; dots {pq,rq,qq,yq}    -> slots {0,1,2,3}
// MODE 2 (final):        no Q store; dot {pq}           -> slot 0
#define SWZ(x) ((x) ^ ((((x) >> 6) & 3) << 4))

__device__ __forceinline__ void stage_half(const char* grows, int kbyte,
                                           char* ldsbase, int tid, int wave) {
  #pragma unroll
  for (int q = 0; q < 2; ++q) {
    int off = q * 4096 + tid * 16;
    int loff = SWZ(off);
    int r = loff >> 6, c = loff & 63;
    gl_lds16(grows + (size_t)r * (KDIM * 2) + kbyte + c,
             ldsbase + q * 4096 + wave * 1024);   // wave-uniform dest
  }
}

template <int MODE>
__global__ __launch_bounds__(256) void gemm8p(
    const unsigned short* __restrict__ A,   // p (Rb for it0, else Pb) [M][KDIM]
    const unsigned short* __restrict__ Bm,  // Khat [8192][KDIM] bf16
    unsigned short* __restrict__ Cq,        // Q [M][8192] bf16
    int gy,
    const unsigned short* __restrict__ Rm,  // residual (MODE 1)
    const float* __restrict__ y,            // train_y [8192] f32
    float* __restrict__ pq8)                // [M][8] dot slots (atomic)
{
  __shared__ char Ab[2][2][8192];
  __shared__ char Bb[2][2][8192];
  int tid = threadIdx.x, lane = tid & 63, wave = tid >> 6;
  int wm = wave >> 1, wn = wave & 1;

  int nwg = gridDim.x;
  int orig = blockIdx.x;
  int wgid = (orig & 7) * (nwg >> 3) + (orig >> 3);
  int bx = wgid / gy, by = wgid % gy;

  const char* bA = (const char*)(A  + (size_t)(by * 128) * KDIM);
  const char* bB = (const char*)(Bm + (size_t)(bx * 128) * KDIM);

  int aoff[4], boff[4];
  #pragma unroll
  for (int f = 0; f < 4; ++f) {
    int ab = (wm * 64 + f * 16 + (lane & 15)) * 64 + (lane >> 4) * 16;
    aoff[f] = SWZ(ab);
    int bb = (wn * 64 + f * 16 + (lane & 15)) * 64 + (lane >> 4) * 16;
    boff[f] = SWZ(bb);
  }

  f32x4 acc[4][4] = {};

#define LDA(p, kk, mf) (*(const bf16x8*)(&Ab[p][kk][0] + aoff[mf]))
#define LDB(p, kk, nf) (*(const bf16x8*)(&Bb[p][kk][0] + boff[nf]))
#define BAR() __builtin_amdgcn_s_barrier()
#define FENCE4() asm volatile("s_waitcnt vmcnt(4)" ::: "memory")
#define FENCE0() asm volatile("s_waitcnt vmcnt(0)" ::: "memory")
#define MFMA8(x, y_, mb, B0, B1, B2, B3)                                          \
  acc[mb][0]   = __builtin_amdgcn_mfma_f32_16x16x32_bf16(x, B0, acc[mb][0],0,0,0);\
  acc[mb][1]   = __builtin_amdgcn_mfma_f32_16x16x32_bf16(x, B1, acc[mb][1],0,0,0);\
  acc[mb][2]   = __builtin_amdgcn_mfma_f32_16x16x32_bf16(x, B2, acc[mb][2],0,0,0);\
  acc[mb][3]   = __builtin_amdgcn_mfma_f32_16x16x32_bf16(x, B3, acc[mb][3],0,0,0);\
  acc[mb+1][0] = __builtin_amdgcn_mfma_f32_16x16x32_bf16(y_, B0, acc[mb+1][0],0,0,0);\
  acc[mb+1][1] = __builtin_amdgcn_mfma_f32_16x16x32_bf16(y_, B1, acc[mb+1][1],0,0,0);\
  acc[mb+1][2] = __builtin_amdgcn_mfma_f32_16x16x32_bf16(y_, B2, acc[mb+1][2],0,0,0);\
  acc[mb+1][3] = __builtin_amdgcn_mfma_f32_16x16x32_bf16(y_, B3, acc[mb+1][3],0,0,0);

  stage_half(bB, 0,  &Bb[0][0][0], tid, wave);
  stage_half(bA, 0,  &Ab[0][0][0], tid, wave);
  stage_half(bB, 64, &Bb[0][1][0], tid, wave);
  stage_half(bA, 64, &Ab[0][1][0], tid, wave);
  FENCE4();
  BAR();

#define TILE(p, t)                                                              \
  {                                                                             \
    const bool st = (t) + 1 < NT;                                               \
    const int kb1 = ((t) + 1) * 128;                                            \
    if (st) stage_half(bB, kb1, &Bb[(p)^1][0][0], tid, wave);                   \
    bf16x8 b00 = LDB(p,0,0), b01 = LDB(p,0,1), b02 = LDB(p,0,2), b03 = LDB(p,0,3);\
    bf16x8 a00 = LDA(p,0,0), a01 = LDA(p,0,1);                                  \
    BAR();                                                                      \
    __builtin_amdgcn_s_setprio(1);                                              \
    MFMA8(a00, a01, 0, b00, b01, b02, b03);                                     \
    __builtin_amdgcn_s_setprio(0);                                              \
    BAR();                                                                      \
    if (st) stage_half(bA, kb1, &Ab[(p)^1][0][0], tid, wave);                   \
    bf16x8 a02 = LDA(p,0,2), a03 = LDA(p,0,3);                                  \
    BAR();                                                                      \
    __builtin_amdgcn_s_setprio(1);                                              \
    MFMA8(a02, a03, 2, b00, b01, b02, b03);                                     \
    __builtin_amdgcn_s_setprio(0);                                              \
    FENCE4();                                                                   \
    BAR();                                                                      \
    if (st) stage_half(bB, kb1 + 64, &Bb[(p)^1][1][0], tid, wave);              \
    bf16x8 b10 = LDB(p,1,0), b11 = LDB(p,1,1), b12 = LDB(p,1,2), b13 = LDB(p,1,3);\
    bf16x8 a10 = LDA(p,1,0), a11 = LDA(p,1,1);                                  \
    BAR();                                                                      \
    __builtin_amdgcn_s_setprio(1);                                              \
    MFMA8(a10, a11, 0, b10, b11, b12, b13);                                     \
    __builtin_amdgcn_s_setprio(0);                                              \
    BAR();                                                                      \
    if (st) stage_half(bA, kb1 + 64, &Ab[(p)^1][1][0], tid, wave);              \
    bf16x8 a12 = LDA(p,1,2), a13 = LDA(p,1,3);                                  \
    BAR();                                                                      \
    __builtin_amdgcn_s_setprio(1);                                              \
    MFMA8(a12, a13, 2, b10, b11, b12, b13);                                     \
    __builtin_amdgcn_s_setprio(0);                                              \
    FENCE4();                                                                   \
    BAR();                                                                      \
  }

  for (int t = 0; t < NT; t += 2) {
    TILE(0, t)
    TILE(1, t + 1)
  }

  int bm = by * 128, bn = bx * 128;
  // Q store (verified C/D mapping: col = lane&15, row = (lane>>4)*4 + reg)
  if (MODE != 2) {
    #pragma unroll
    for (int i = 0; i < 4; ++i) {
      #pragma unroll
      for (int jf = 0; jf < 4; ++jf) {
        int row = bm + wm * 64 + i * 16 + (lane >> 4) * 4;
        int col = bn + wn * 64 + jf * 16 + (lane & 15);
        #pragma unroll
        for (int rg = 0; rg < 4; ++rg)
          Cq[(size_t)(row + rg) * KDIM + col] = f2bf(acc[i][jf][rg]);
      }
    }
  }

  // ---- fused dot epilogue: repurpose gemm LDS for coalesced P/R tile staging ----
  FENCE0();            // drain outstanding global_load_lds before overwriting LDS
  BAR();
  unsigned short* Pl = (unsigned short*)&Ab[0][0][0];   // 32 KB: P[128][128]
  unsigned short* Rl = (unsigned short*)&Bb[0][0][0];   // 32 KB: R[128][128]
  {
    int r = tid >> 4;
    int cb = (tid & 15) * 8;
    #pragma unroll
    for (int pass = 0; pass < 8; ++pass) {
      int row = pass * 16 + r;
      *(bf16x8*)&Pl[row * 128 + cb] =
          *(const bf16x8*)&A[(size_t)(bm + row) * KDIM + bn + cb];
      if (MODE == 1)
        *(bf16x8*)&Rl[row * 128 + cb] =
            *(const bf16x8*)&Rm[(size_t)(bm + row) * KDIM + bn + cb];
    }
  }
  __syncthreads();

  float yv[4];
  if (MODE != 2) {
    #pragma unroll
    for (int jf = 0; jf < 4; ++jf) yv[jf] = y[bn + wn * 64 + jf * 16 + (lane & 15)];
  }

  #pragma unroll
  for (int i = 0; i < 4; ++i) {
    #pragma unroll
    for (int rg = 0; rg < 4; ++rg) {
      int lrow = wm * 64 + i * 16 + (lane >> 4) * 4 + rg;
      float s0 = 0.f, s1 = 0.f, s2 = 0.f, s3 = 0.f, s4 = 0.f;
      #pragma unroll
      for (int jf = 0; jf < 4; ++jf) {
        int lcol = wn * 64 + jf * 16 + (lane & 15);
        float qv = (MODE == 2) ? acc[i][jf][rg] : rnd_bf(acc[i][jf][rg]);
        float pv = bf2f(Pl[lrow * 128 + lcol]);
        s0 += pv * qv;
        if (MODE == 0) {
          s1 += qv * qv; s2 += yv[jf] * qv; s3 += pv * pv; s4 += yv[jf] * pv;
        } else if (MODE == 1) {
          float rv = bf2f(Rl[lrow * 128 + lcol]);
          s1 += rv * qv; s2 += qv * qv; s3 += yv[jf] * qv;
        }
      }
      #pragma unroll
      for (int off = 1; off < 16; off <<= 1) {
        s0 += __shfl_xor(s0, off);
        if (MODE != 2) { s1 += __shfl_xor(s1, off); s2 += __shfl_xor(s2, off); }
        if (MODE == 0) { s3 += __shfl_xor(s3, off); s4 += __shfl_xor(s4, off); }
        if (MODE == 1) { s3 += __shfl_xor(s3, off); }
      }
      if ((lane & 15) == 0) {
        float* d = &pq8[(size_t)(bm + lrow) * 8];
        atomicAdd(&d[0], s0);
        if (MODE == 0) { atomicAdd(&d[2], s1); atomicAdd(&d[3], s2);
                         atomicAdd(&d[4], s3); atomicAdd(&d[5], s4); }
        if (MODE == 1) { atomicAdd(&d[1], s1); atomicAdd(&d[2], s2);
                         atomicAdd(&d[3], s3); }
      }
    }
  }
#undef TILE
#undef MFMA8
#undef FENCE4
#undef FENCE0
#undef BAR
#undef LDA
#undef LDB
}

// ---- per-column scalar recurrence; zeroes dot slots for next iter ----
template <bool FIRST>
__global__ void cg_scal(float* __restrict__ pq8, float* __restrict__ scal,
                        float2* __restrict__ ab, int C)
{
  int c = blockIdx.x * 256 + threadIdx.x;
  if (c >= C) return;
  float* d = &pq8[(size_t)c * 8];
  float pqv = d[0], rqv = FIRST ? d[0] : d[1], qq = d[2], yq = d[3];
  float rr, yp, yr, mean, bx;
  if (FIRST) {
    rr = d[4]; yp = d[5]; yr = d[5]; mean = 0.f; bx = 0.f;
  } else {
    rr = scal[c*8+0]; yp = scal[c*8+1]; yr = scal[c*8+2];
    mean = scal[c*8+3]; bx = scal[c*8+4];
  }
  float alpha = rr / fmaxf(pqv, 1e-30f);
  mean += alpha * yp;
  bx   += alpha * rr;
  float rrn = fmaxf(rr - 2.f * alpha * rqv + alpha * alpha * qq, 0.f);
  float yrn = yr - alpha * yq;
  float beta = rrn / fmaxf(rr, 1e-30f);
  float ypn  = yrn + beta * yp;
  scal[c*8+0] = rrn; scal[c*8+1] = ypn; scal[c*8+2] = yrn;
  scal[c*8+3] = mean; scal[c*8+4] = bx;
  ab[c] = make_float2(alpha, beta);
  #pragma unroll
  for (int k = 0; k < 6; ++k) d[k] = 0.f;
}

// ---- streaming update: r' = r - alpha*q ; p' = r' + beta*p_in ----
__global__ __launch_bounds__(256) void cg_upd(
    const unsigned short* __restrict__ Q, unsigned short* __restrict__ R,
    const unsigned short* __restrict__ Pin, unsigned short* __restrict__ Pout,
    const float2* __restrict__ ab, int nchunk)
{
  int stride = gridDim.x * 256;
  for (int ch = blockIdx.x * 256 + threadIdx.x; ch < nchunk; ch += stride) {
    int c = ch >> 10;                     // 1024 16B-chunks per column
    float2 a = ab[c];
    size_t off = (size_t)ch * 8;
    bf16x8 q8 = *(const bf16x8*)&Q[off];
    bf16x8 r8 = *(const bf16x8*)&R[off];
    bf16x8 p8 = *(const bf16x8*)&Pin[off];
    bf16x8 wr, wp;
    #pragma unroll
    for (int e = 0; e < 8; ++e) {
      float rn = bf2f((unsigned short)r8[e]) - a.x * bf2f((unsigned short)q8[e]);
      unsigned short hb = f2bf(rn);
      wr[e] = (short)hb;
      wp[e] = (short)f2bf(bf2f(hb) + a.y * bf2f((unsigned short)p8[e]));
    }
    *(bf16x8*)&R[off] = wr;
    *(bf16x8*)&Pout[off] = wp;
  }
}

// ---- final outputs; zeroes dot slots for next chunk/replay ----
__global__ void final_out(float* __restrict__ pq8, const float* __restrict__ scal,
                          const float* __restrict__ osc, const float* __restrict__ noi,
                          float* __restrict__ out, int c0, int C)
{
  int c = blockIdx.x * 256 + threadIdx.x;
  if (c >= C) return;
  float* d = &pq8[(size_t)c * 8];
  float rr = scal[c*8+0], yp = scal[c*8+1];
  float mean = scal[c*8+3], bx = scal[c*8+4];
  float alpha = rr / fmaxf(d[0], 1e-30f);
  mean += alpha * yp;
  bx   += alpha * rr;
  out[c0 + c] = mean;
  out[N_TEST + c0 + c] = osc[0] + noi[0] - bx;
  #pragma unroll
  for (int k = 0; k < 6; ++k) d[k] = 0.f;
}

extern "C" void kernel_launch(void* const* d_in, const int* in_sizes, int n_in,
                              void* d_out, int out_size, void* d_ws, size_t ws_size,
                              hipStream_t stream) {
  const float* tx = (const float*)d_in[0];
  const float* ty = (const float*)d_in[1];
  const float* xx = (const float*)d_in[2];
  const float* os = (const float*)d_in[3];
  const float* ls = (const float*)d_in[4];
  const float* ns = (const float*)d_in[5];
  float* out = (float*)d_out;
  (void)in_sizes; (void)n_in; (void)out_size;

  auto pad = [](size_t x) { return (x + 255) & ~(size_t)255; };
  size_t fixed = pad((size_t)N_TRAIN * KDIM * 2)
               + pad((size_t)N_TRAIN * DIM * 4) + pad((size_t)N_TRAIN * 4)
               + pad((size_t)N_TEST * DIM * 4) + pad((size_t)N_TEST * 4);
  int C = 4096;
  while (C > 128) {
    size_t tot = fixed + 3 * pad((size_t)C * KDIM * 2)
               + pad((size_t)C * 32) + pad((size_t)C * 32) + pad((size_t)C * 8);
    if (tot <= ws_size) break;
    C >>= 1;
  }

  char* w = (char*)d_ws;
  auto alloc = [&](size_t bytes) { char* p = w; w += ((bytes + 255) & ~(size_t)255); return p; };
  unsigned short* Kb = (unsigned short*)alloc((size_t)N_TRAIN * KDIM * 2);
  float* As = (float*)alloc((size_t)N_TRAIN * DIM * 4);
  float* an = (float*)alloc((size_t)N_TRAIN * 4);
  float* Bs = (float*)alloc((size_t)N_TEST * DIM * 4);
  float* bn = (float*)alloc((size_t)N_TEST * 4);
  unsigned short* Rb = (unsigned short*)alloc((size_t)C * KDIM * 2);
  unsigned short* Pb = (unsigned short*)alloc((size_t)C * KDIM * 2);
  unsigned short* Qb = (unsigned short*)alloc((size_t)C * KDIM * 2);
  float* scal = (float*)alloc((size_t)C * 32);
  float* pq8  = (float*)alloc((size_t)C * 32);
  float2* ab  = (float2*)alloc((size_t)C * 8);

  hipMemsetAsync(pq8, 0, (size_t)C * 32, stream);

  prep_kernel<<<48, 256, 0, stream>>>(tx, xx, ls, As, an, Bs, bn);

  build_kernel<true><<<dim3(KDIM / 512, N_TRAIN / 128), 256, 0, stream>>>(
      As, an, As, an, Kb, os, ns);

  int nchunk = C * (KDIM / 8);
  for (int c0 = 0; c0 < N_TEST; c0 += C) {
    build_kernel<false><<<dim3(KDIM / 512, C / 128), 256, 0, stream>>>(
        Bs + (size_t)c0 * DIM, bn + c0, As, an, Rb, os, ns);
    int gy = C / 128;
    dim3 gg(64 * gy);
    int scb = (C + 255) / 256;
    for (int it = 0; it < CG_ITERS; ++it) {
      if (it == 0) {
        gemm8p<0><<<gg, 256, 0, stream>>>(Rb, Kb, Qb, gy, Rb, ty, pq8);
        cg_scal<true><<<scb, 256, 0, stream>>>(pq8, scal, ab, C);
        cg_upd<<<2048, 256, 0, stream>>>(Qb, Rb, Rb, Pb, ab, nchunk);
      } else if (it < CG_ITERS - 1) {
        gemm8p<1><<<gg, 256, 0, stream>>>(Pb, Kb, Qb, gy, Rb, ty, pq8);
        cg_scal<false><<<scb, 256, 0, stream>>>(pq8, scal, ab, C);
        cg_upd<<<2048, 256, 0, stream>>>(Qb, Rb, Pb, Pb, ab, nchunk);
      } else {
        gemm8p<2><<<gg, 256, 0, stream>>>(Pb, Kb, Qb, gy, Rb, ty, pq8);
        final_out<<<scb, 256, 0, stream>>>(pq8, scal, os, ns, out, c0, C);
      }
    }
  }
}

// Round 10
// 2458.343 us; speedup vs baseline: 1.7032x; 1.7032x over previous
//
#include <hip/hip_runtime.h>
#include <stdint.h>

// GP posterior via batched CG. Khat bf16 (128 MB). Matvec = 256x256x64 8-phase
// counted-vmcnt MFMA GEMM (m201-style template, hand-verified stage/fence ledger).
// Vector phase = r5's proven monolithic cg_step. Final iteration's pAp fused
// into gemm epilogue (free, proven r5).

#define N_TRAIN 8192
#define N_TEST  4096
#define DIM     16
#define KDIM    8192
#define CG_ITERS 5
#define NT      (KDIM / 64)   // 128 K-tiles of BK=64

using f32x4  = __attribute__((ext_vector_type(4))) float;
using bf16x8 = __attribute__((ext_vector_type(8))) short;

static __device__ __forceinline__ unsigned short f2bf(float f) {
  unsigned u = __float_as_uint(f);
  u = (u + 0x7FFFu + ((u >> 16) & 1u)) >> 16;   // RNE
  return (unsigned short)u;
}
static __device__ __forceinline__ float bf2f(unsigned short h) {
  return __uint_as_float(((unsigned)h) << 16);
}

__device__ __forceinline__ void gl_lds16(const void* g, void* l) {
  __builtin_amdgcn_global_load_lds(
      (const __attribute__((address_space(1))) unsigned int*)g,
      (__attribute__((address_space(3))) unsigned int*)l, 16, 0, 0);
}

__device__ __forceinline__ void block_reduce2(float& a, float& b, float* sbuf) {
  #pragma unroll
  for (int off = 32; off > 0; off >>= 1) {
    a += __shfl_down(a, off);
    b += __shfl_down(b, off);
  }
  int lane = threadIdx.x & 63, w = threadIdx.x >> 6;
  __syncthreads();
  if (lane == 0) { sbuf[w * 2] = a; sbuf[w * 2 + 1] = b; }
  __syncthreads();
  a = sbuf[0] + sbuf[2] + sbuf[4] + sbuf[6];
  b = sbuf[1] + sbuf[3] + sbuf[5] + sbuf[7];
}

// ---- prep: rows scaled by 1/lengthscale + squared norms ----
__global__ void prep_kernel(const float* __restrict__ tx, const float* __restrict__ xx,
                            const float* __restrict__ ls,
                            float* __restrict__ As, float* __restrict__ an,
                            float* __restrict__ Bs, float* __restrict__ bn) {
  int i = blockIdx.x * 256 + threadIdx.x;
  if (i < N_TRAIN) {
    float s = 0.f;
    #pragma unroll
    for (int d = 0; d < DIM; ++d) {
      float v = tx[(size_t)i * DIM + d] / ls[d];
      As[(size_t)i * DIM + d] = v; s += v * v;
    }
    an[i] = s;
  } else if (i < N_TRAIN + N_TEST) {
    int j = i - N_TRAIN;
    float s = 0.f;
    #pragma unroll
    for (int d = 0; d < DIM; ++d) {
      float v = xx[(size_t)j * DIM + d] / ls[d];
      Bs[(size_t)j * DIM + d] = v; s += v * v;
    }
    bn[j] = s;
  }
}

// ---- kernel-matrix builder: 2 cols/thread, rows in 2-row chunks ----
template <bool NOISE>
__global__ __launch_bounds__(256) void build_kernel(
    const float* __restrict__ RI, const float* __restrict__ nI,
    const float* __restrict__ RJ, const float* __restrict__ nJ,
    unsigned short* __restrict__ O1,
    const float* __restrict__ osc, const float* __restrict__ noi)
{
  __shared__ float aI[128 * DIM];
  __shared__ float sI[128];
  int t = threadIdx.x;
  int j0 = blockIdx.x * 512, i0 = blockIdx.y * 128;
  for (int e = t; e < 128 * DIM; e += 256) aI[e] = RI[(size_t)i0 * DIM + e];
  if (t < 128) sI[t] = nI[i0 + t];
  __syncthreads();

  int ja = j0 + t, jb = ja + 256;
  f32x4 aj0[4], aj1[4];
  const f32x4* RJa = (const f32x4*)(RJ + (size_t)ja * DIM);
  const f32x4* RJb = (const f32x4*)(RJ + (size_t)jb * DIM);
  #pragma unroll
  for (int q = 0; q < 4; ++q) { aj0[q] = RJa[q]; aj1[q] = RJb[q]; }
  float nja = nJ[ja], njb = nJ[jb];
  float s = osc[0], sn = noi[0];

  for (int ic = 0; ic < 128; ic += 2) {
    f32x4 rv[2][4];
    #pragma unroll
    for (int r = 0; r < 2; ++r)
      #pragma unroll
      for (int q = 0; q < 4; ++q)
        rv[r][q] = *(const f32x4*)&aI[(ic + r) * DIM + q * 4];
    #pragma unroll
    for (int r = 0; r < 2; ++r) {
      int i = ic + r;
      float d0 = 0.f, d1 = 0.f;
      #pragma unroll
      for (int q = 0; q < 4; ++q) {
        f32x4 ai = rv[r][q];
        d0 += ai[0]*aj0[q][0] + ai[1]*aj0[q][1] + ai[2]*aj0[q][2] + ai[3]*aj0[q][3];
        d1 += ai[0]*aj1[q][0] + ai[1]*aj1[q][1] + ai[2]*aj1[q][2] + ai[3]*aj1[q][3];
      }
      float d2a = fmaxf(sI[i] + nja - 2.f * d0, 0.f);
      float d2b = fmaxf(sI[i] + njb - 2.f * d1, 0.f);
      float va = s * __expf(-0.5f * d2a);
      float vb = s * __expf(-0.5f * d2b);
      if (NOISE && (i0 + i == ja)) va += sn;
      if (NOISE && (i0 + i == jb)) vb += sn;
      size_t rowb = (size_t)(i0 + i) * KDIM;
      O1[rowb + ja] = f2bf(va); O1[rowb + jb] = f2bf(vb);
    }
  }
}

// ============  256x256 8-phase pipelined MFMA GEMM (counted vmcnt)  ============
// Q[M][8192] = P[M][8192] * Khat^T. 512 thr (2M x 4N waves), per-wave 128x64.
// LDS [2 buf][2 half][128 rows x 64 bf16] for A and B = 128 KB.
// Swizzle: byte ^= ((row&7)<<4) within 128B rows (both sides, rule #21).

__device__ __forceinline__ void stage_h(const char* gtile, int kbyte,
                                        char* ldsdst, int tid, int wave) {
  #pragma unroll
  for (int q = 0; q < 2; ++q) {
    int o = q * 8192 + tid * 16;
    int r = o >> 7;
    int c = (o & 127) ^ ((r & 7) << 4);
    gl_lds16(gtile + (size_t)r * (KDIM * 2) + kbyte + c,
             ldsdst + q * 8192 + wave * 1024);   // wave-uniform dest, HW adds lane*16
  }
}

template <int FINAL>
__global__ __launch_bounds__(512, 1) void gemm256(
    const unsigned short* __restrict__ A,   // p (Rb for it0, else Pb) [M][KDIM]
    const unsigned short* __restrict__ Bm,  // Khat [8192][KDIM] bf16
    unsigned short* __restrict__ Cq,        // Q [M][8192] bf16
    int gy, float* __restrict__ pq)
{
  __shared__ char Ab[2][2][16384];   // [buf][half][128x64 bf16] = 64 KB
  __shared__ char Bb[2][2][16384];   // 64 KB
  const int tid = threadIdx.x, lane = tid & 63, wave = tid >> 6;
  const int wm = wave >> 2, wn = wave & 3;          // 2M x 4N
  const int nwg = gridDim.x, orig = blockIdx.x;
  const int wgid = (orig & 7) * (nwg >> 3) + (orig >> 3);   // XCD-chunked
  const int bx = wgid / gy, by = wgid % gy;
  const size_t HALF = (size_t)128 * KDIM * 2;

  const char* bA = (const char*)(A  + (size_t)(by * 256) * KDIM);
  const char* bB = (const char*)(Bm + (size_t)(bx * 256) * KDIM);

  // fragment LDS byte offsets within a 16KB half
  const int ar = wm * 64 + (lane & 15);
  const int br = wn * 32 + (lane & 15);
  const int hi = (lane >> 4) * 16;
  int aoff[4][2], boff[2][2];
  #pragma unroll
  for (int mf = 0; mf < 4; ++mf)
    #pragma unroll
    for (int kk = 0; kk < 2; ++kk)
      aoff[mf][kk] = (ar + mf * 16) * 128 + ((hi + kk * 64) ^ ((ar & 7) << 4));
  #pragma unroll
  for (int nf = 0; nf < 2; ++nf)
    #pragma unroll
    for (int kk = 0; kk < 2; ++kk)
      boff[nf][kk] = (br + nf * 16) * 128 + ((hi + kk * 64) ^ ((br & 7) << 4));

  f32x4 acc[2][2][4][2] = {};   // [mh][nh][mf][nf]
  bf16x8 aR[4][2], bR[2][2][2]; // aR[mf][kk], bR[nh][nf][kk]

#define BAR() __builtin_amdgcn_s_barrier()
#define PRIO1 __builtin_amdgcn_s_setprio(1)
#define PRIO0 __builtin_amdgcn_s_setprio(0)
#define FENCE8() asm volatile("s_waitcnt vmcnt(8)" ::: "memory")
#define FENCE6() asm volatile("s_waitcnt vmcnt(6)" ::: "memory")
#define FENCE0() asm volatile("s_waitcnt vmcnt(0)" ::: "memory")
#define STAGE_A(buf, mh, kb) stage_h(bA + ((mh) ? HALF : 0), kb, &Ab[buf][mh][0], tid, wave)
#define STAGE_B(buf, mh, kb) stage_h(bB + ((mh) ? HALF : 0), kb, &Bb[buf][mh][0], tid, wave)
#define LOAD_A(buf, mh)                                                        \
  { _Pragma("unroll") for (int mf = 0; mf < 4; ++mf)                           \
      _Pragma("unroll") for (int kk = 0; kk < 2; ++kk)                         \
        aR[mf][kk] = *(const bf16x8*)(&Ab[buf][mh][0] + aoff[mf][kk]); }
#define LOAD_B(buf, nh)                                                        \
  { _Pragma("unroll") for (int nf = 0; nf < 2; ++nf)                           \
      _Pragma("unroll") for (int kk = 0; kk < 2; ++kk)                         \
        bR[nh][nf][kk] = *(const bf16x8*)(&Bb[buf][nh][0] + boff[nf][kk]); }
#define MFMA16(mh, nh)                                                         \
  { _Pragma("unroll") for (int kk = 0; kk < 2; ++kk)                           \
      _Pragma("unroll") for (int mf = 0; mf < 4; ++mf)                         \
        _Pragma("unroll") for (int nf = 0; nf < 2; ++nf)                       \
          acc[mh][nh][mf][nf] = __builtin_amdgcn_mfma_f32_16x16x32_bf16(       \
              aR[mf][kk], bR[nh][nf][kk], acc[mh][nh][mf][nf], 0, 0, 0); }

  // prologue: tiles 0 (buf0) and 1 (buf1); order matters for the FIFO ledger
  STAGE_A(0, 0, 0);   STAGE_B(0, 0, 0);   STAGE_B(0, 1, 0);   STAGE_A(0, 1, 0);
  STAGE_A(1, 0, 128); STAGE_B(1, 0, 128); STAGE_B(1, 1, 128); STAGE_A(1, 1, 128);
  FENCE6();            // completes tile0 fully + A0(1); leaves B0,B1,A1(1) in flight
  BAR();

  for (int t = 0; t < NT; t += 2) {
    const bool g = (t + 2 < NT);
    const int kb2 = (t + 2) * 128, kb3 = (t + 3) * 128;
    // ph1: tile t quad(0,0) — no stage
    LOAD_A(0, 0); LOAD_B(0, 0);
    BAR(); PRIO1; MFMA16(0, 0); PRIO0; BAR();
    // ph2: quad(0,1); stage A0(t+2) [A0(t) consumed in ph1]
    if (g) STAGE_A(0, 0, kb2);
    LOAD_B(0, 1);
    BAR(); PRIO1; MFMA16(0, 1); PRIO0; BAR();
    // ph3: quad(1,0); stage B0(t+2) [B0(t) consumed ph1]
    if (g) STAGE_B(0, 0, kb2);
    LOAD_A(0, 1);
    BAR(); PRIO1; MFMA16(1, 0); PRIO0; BAR();
    // ph4: quad(1,1); stage B1(t+2)+A1(t+2) [consumed ph2/ph3]; fence -> tile t+1 ready
    if (g) { STAGE_B(0, 1, kb2); STAGE_A(0, 1, kb2); }
    BAR(); PRIO1; MFMA16(1, 1); PRIO0;
    if (g) { FENCE8(); } else { FENCE0(); }
    BAR();
    // ph5: tile t+1 quad(0,0) — no stage
    LOAD_A(1, 0); LOAD_B(1, 0);
    BAR(); PRIO1; MFMA16(0, 0); PRIO0; BAR();
    // ph6: quad(0,1); stage A0(t+3)
    if (g) STAGE_A(1, 0, kb3);
    LOAD_B(1, 1);
    BAR(); PRIO1; MFMA16(0, 1); PRIO0; BAR();
    // ph7: quad(1,0); stage B0(t+3)
    if (g) STAGE_B(1, 0, kb3);
    LOAD_A(1, 1);
    BAR(); PRIO1; MFMA16(1, 0); PRIO0; BAR();
    // ph8: quad(1,1); stage B1(t+3)+A1(t+3); fence -> tile t+2 fully done + A0(t+3)
    if (g) { STAGE_B(1, 1, kb3); STAGE_A(1, 1, kb3); }
    BAR(); PRIO1; MFMA16(1, 1); PRIO0;
    if (g) { FENCE6(); }
    BAR();
  }

  const int bm = by * 256, bn = bx * 256;
  if (!FINAL) {
    // C/D mapping (verified): col = lane&15, row = (lane>>4)*4 + reg
    #pragma unroll
    for (int mh = 0; mh < 2; ++mh)
      #pragma unroll
      for (int nh = 0; nh < 2; ++nh)
        #pragma unroll
        for (int mf = 0; mf < 4; ++mf)
          #pragma unroll
          for (int nf = 0; nf < 2; ++nf) {
            int row = bm + mh * 128 + wm * 64 + mf * 16 + (lane >> 4) * 4;
            int col = bn + nh * 128 + wn * 32 + nf * 16 + (lane & 15);
            #pragma unroll
            for (int rg = 0; rg < 4; ++rg)
              Cq[(size_t)(row + rg) * KDIM + col] = f2bf(acc[mh][nh][mf][nf][rg]);
          }
  } else {
    // final iteration: only pAp. pq[row] += sum_col P[row][col]*Q[row][col]
    #pragma unroll
    for (int mh = 0; mh < 2; ++mh)
      #pragma unroll
      for (int mf = 0; mf < 4; ++mf)
        #pragma unroll
        for (int rg = 0; rg < 4; ++rg) {
          int row = bm + mh * 128 + wm * 64 + mf * 16 + (lane >> 4) * 4 + rg;
          float v = 0.f;
          #pragma unroll
          for (int nh = 0; nh < 2; ++nh)
            #pragma unroll
            for (int nf = 0; nf < 2; ++nf) {
              int col = bn + nh * 128 + wn * 32 + nf * 16 + (lane & 15);
              v += acc[mh][nh][mf][nf][rg] * bf2f(A[(size_t)row * KDIM + col]);
            }
          v += __shfl_xor(v, 1); v += __shfl_xor(v, 2);
          v += __shfl_xor(v, 4); v += __shfl_xor(v, 8);
          if ((lane & 15) == 0) atomicAdd(&pq[row], v);
        }
  }
#undef MFMA16
#undef LOAD_B
#undef LOAD_A
#undef STAGE_B
#undef STAGE_A
#undef FENCE0
#undef FENCE6
#undef FENCE8
#undef PRIO0
#undef PRIO1
#undef BAR
}

// ---- one CG step (r5-proven): all loads up front, 2 reductions, fused updates ----
template <bool FIRST>
__global__ __launch_bounds__(256) void cg_step(
    const unsigned short* __restrict__ Q, unsigned short* __restrict__ R,
    unsigned short* __restrict__ P, const float* __restrict__ y,
    float* __restrict__ scal, float* __restrict__ pq)
{
  __shared__ float sbuf[8];
  int c = blockIdx.x, t = threadIdx.x;
  size_t base = (size_t)c * KDIM;

  bf16x8 q8[4], r8[4], p8[4];
  #pragma unroll
  for (int k = 0; k < 4; ++k) q8[k] = *(const bf16x8*)&Q[base + k * 2048 + t * 8];
  #pragma unroll
  for (int k = 0; k < 4; ++k) r8[k] = *(const bf16x8*)&R[base + k * 2048 + t * 8];
  if (FIRST) {
    #pragma unroll
    for (int k = 0; k < 4; ++k) p8[k] = r8[k];
  } else {
    #pragma unroll
    for (int k = 0; k < 4; ++k) p8[k] = *(const bf16x8*)&P[base + k * 2048 + t * 8];
  }

  // pass 1: pAp (+ rr0, y.b on FIRST via second slot)
  float s1 = 0.f, sx = 0.f;
  #pragma unroll
  for (int k = 0; k < 4; ++k)
    #pragma unroll
    for (int e = 0; e < 8; ++e) {
      float qv = bf2f((unsigned short)q8[k][e]);
      float pv = bf2f((unsigned short)p8[k][e]);
      s1 += pv * qv;
      if (FIRST) sx += pv * pv;
    }
  block_reduce2(s1, sx, sbuf);

  float rr, ypv, mean, bx;
  if (FIRST) {
    // rr0 = ||b||^2 = sx ; yp0 = y.b computed below with y loads in pass 2
    rr = sx; mean = 0.f; bx = 0.f; ypv = 0.f;   // ypv filled after pass2 reduce
  } else {
    rr  = scal[c * 4 + 0];
    ypv = scal[c * 4 + 1];
    mean = scal[c * 4 + 2];
    bx   = scal[c * 4 + 3];
  }

  float alpha = rr / fmaxf(s1, 1e-30f);

  // pass 2: r' = r - alpha*q (write) ; rr', y.r' (on rounded values); FIRST also y.b
  float s2 = 0.f, s3 = 0.f, yb = 0.f;
  #pragma unroll
  for (int k = 0; k < 4; ++k) {
    int j = k * 2048 + t * 8;
    f32x4 y4a = *(const f32x4*)&y[j];
    f32x4 y4b = *(const f32x4*)&y[j + 4];
    bf16x8 w;
    #pragma unroll
    for (int e = 0; e < 8; ++e) {
      float yv = (e < 4) ? y4a[e] : y4b[e - 4];
      if (FIRST) yb += yv * bf2f((unsigned short)p8[k][e]);
      float rn = bf2f((unsigned short)r8[k][e]) -
                 alpha * bf2f((unsigned short)q8[k][e]);
      unsigned short hb = f2bf(rn);
      float rq = bf2f(hb);
      w[e] = (short)hb;
      s2 += rq * rq; s3 += rq * yv;
    }
    r8[k] = w;
    *(bf16x8*)&R[base + j] = w;
  }
  if (FIRST) {
    block_reduce2(s2, yb, sbuf);
    float s3b = s3, z = 0.f;
    block_reduce2(s3b, z, sbuf);
    s3 = s3b; ypv = yb;
  } else {
    block_reduce2(s2, s3, sbuf);
  }
  mean += alpha * ypv;
  bx   += alpha * rr;
  float beta = s2 / fmaxf(rr, 1e-30f);
  float ypn  = s3 + beta * ypv;

  // pass 3: p' = r' + beta*p (no loads)
  #pragma unroll
  for (int k = 0; k < 4; ++k) {
    int j = k * 2048 + t * 8;
    bf16x8 w;
    #pragma unroll
    for (int e = 0; e < 8; ++e)
      w[e] = (short)f2bf(bf2f((unsigned short)r8[k][e]) +
                         beta * bf2f((unsigned short)p8[k][e]));
    *(bf16x8*)&P[base + j] = w;
  }
  if (t == 0) {
    scal[c * 4 + 0] = s2; scal[c * 4 + 1] = ypn;
    scal[c * 4 + 2] = mean; scal[c * 4 + 3] = bx;
    pq[c] = 0.f;   // zero for the final gemm's atomics
  }
}

// ---- final outputs from pq (pAp of last iteration) + scal ----
__global__ void final_out(const float* __restrict__ pq, const float* __restrict__ scal,
                          const float* __restrict__ osc, const float* __restrict__ noi,
                          float* __restrict__ out, int c0, int C)
{
  int c = blockIdx.x * 256 + threadIdx.x;
  if (c >= C) return;
  float rr = scal[c * 4 + 0], yp = scal[c * 4 + 1];
  float mean = scal[c * 4 + 2], bx = scal[c * 4 + 3];
  float alpha = rr / fmaxf(pq[c], 1e-30f);
  mean += alpha * yp;
  bx   += alpha * rr;
  out[c0 + c] = mean;
  out[N_TEST + c0 + c] = osc[0] + noi[0] - bx;
}

extern "C" void kernel_launch(void* const* d_in, const int* in_sizes, int n_in,
                              void* d_out, int out_size, void* d_ws, size_t ws_size,
                              hipStream_t stream) {
  const float* tx = (const float*)d_in[0];
  const float* ty = (const float*)d_in[1];
  const float* xx = (const float*)d_in[2];
  const float* os = (const float*)d_in[3];
  const float* ls = (const float*)d_in[4];
  const float* ns = (const float*)d_in[5];
  float* out = (float*)d_out;
  (void)in_sizes; (void)n_in; (void)out_size;

  auto pad = [](size_t x) { return (x + 255) & ~(size_t)255; };
  size_t fixed = pad((size_t)N_TRAIN * KDIM * 2)
               + pad((size_t)N_TRAIN * DIM * 4) + pad((size_t)N_TRAIN * 4)
               + pad((size_t)N_TEST * DIM * 4) + pad((size_t)N_TEST * 4);
  int C = 4096;
  while (C > 256) {
    size_t tot = fixed + 3 * pad((size_t)C * KDIM * 2)
               + pad((size_t)C * 16) + pad((size_t)C * 4);
    if (tot <= ws_size) break;
    C >>= 1;
  }

  char* w = (char*)d_ws;
  auto alloc = [&](size_t bytes) { char* p = w; w += ((bytes + 255) & ~(size_t)255); return p; };
  unsigned short* Kb = (unsigned short*)alloc((size_t)N_TRAIN * KDIM * 2);
  float* As = (float*)alloc((size_t)N_TRAIN * DIM * 4);
  float* an = (float*)alloc((size_t)N_TRAIN * 4);
  float* Bs = (float*)alloc((size_t)N_TEST * DIM * 4);
  float* bn = (float*)alloc((size_t)N_TEST * 4);
  unsigned short* Rb = (unsigned short*)alloc((size_t)C * KDIM * 2);
  unsigned short* Pb = (unsigned short*)alloc((size_t)C * KDIM * 2);
  unsigned short* Qb = (unsigned short*)alloc((size_t)C * KDIM * 2);
  float* scal = (float*)alloc((size_t)C * 16);
  float* pq   = (float*)alloc((size_t)C * 4);

  prep_kernel<<<48, 256, 0, stream>>>(tx, xx, ls, As, an, Bs, bn);

  build_kernel<true><<<dim3(KDIM / 512, N_TRAIN / 128), 256, 0, stream>>>(
      As, an, As, an, Kb, os, ns);

  for (int c0 = 0; c0 < N_TEST; c0 += C) {
    build_kernel<false><<<dim3(KDIM / 512, C / 128), 256, 0, stream>>>(
        Bs + (size_t)c0 * DIM, bn + c0, As, an, Rb, os, ns);
    int gy = C / 256;
    dim3 gg(32 * gy);
    int scb = (C + 255) / 256;
    for (int it = 0; it < CG_ITERS; ++it) {
      const unsigned short* Ain = (it == 0) ? Rb : Pb;
      int fin = (it == CG_ITERS - 1) ? 1 : 0;
      if (!fin) {
        gemm256<0><<<gg, 512, 0, stream>>>(Ain, Kb, Qb, gy, pq);
        if (it == 0)
          cg_step<true><<<C, 256, 0, stream>>>(Qb, Rb, Pb, ty, scal, pq);
        else
          cg_step<false><<<C, 256, 0, stream>>>(Qb, Rb, Pb, ty, scal, pq);
      } else {
        gemm256<1><<<gg, 512, 0, stream>>>(Ain, Kb, Qb, gy, pq);
        final_out<<<scb, 256, 0, stream>>>(pq, scal, os, ns, out, c0, C);
      }
    }
  }
}

// Round 11
// 2452.470 us; speedup vs baseline: 1.7072x; 1.0024x over previous
//
#include <hip/hip_runtime.h>
#include <stdint.h>

// GP posterior via batched CG. Khat bf16 (128 MB). Matvec = 256x256x64 8-phase
// counted-vmcnt MFMA GEMM (87% dense peak, r10-verified - DO NOT TOUCH).
// cg_step: single-reduction recurrence form (all dots in pass 1, one reduce,
// fused R'/P' update). Final iteration's pAp fused into gemm epilogue.

#define N_TRAIN 8192
#define N_TEST  4096
#define DIM     16
#define KDIM    8192
#define CG_ITERS 5
#define NT      (KDIM / 64)   // 128 K-tiles of BK=64

using f32x4  = __attribute__((ext_vector_type(4))) float;
using bf16x8 = __attribute__((ext_vector_type(8))) short;

static __device__ __forceinline__ unsigned short f2bf(float f) {
  unsigned u = __float_as_uint(f);
  u = (u + 0x7FFFu + ((u >> 16) & 1u)) >> 16;   // RNE
  return (unsigned short)u;
}
static __device__ __forceinline__ float bf2f(unsigned short h) {
  return __uint_as_float(((unsigned)h) << 16);
}

__device__ __forceinline__ void gl_lds16(const void* g, void* l) {
  __builtin_amdgcn_global_load_lds(
      (const __attribute__((address_space(1))) unsigned int*)g,
      (__attribute__((address_space(3))) unsigned int*)l, 16, 0, 0);
}

template <int N>
__device__ __forceinline__ void block_reduceN(float* v, float* sbuf) {
  #pragma unroll
  for (int off = 32; off > 0; off >>= 1)
    #pragma unroll
    for (int i = 0; i < N; ++i) v[i] += __shfl_down(v[i], off);
  int lane = threadIdx.x & 63, w = threadIdx.x >> 6;
  if (lane == 0)
    #pragma unroll
    for (int i = 0; i < N; ++i) sbuf[w * N + i] = v[i];
  __syncthreads();
  #pragma unroll
  for (int i = 0; i < N; ++i)
    v[i] = sbuf[i] + sbuf[N + i] + sbuf[2 * N + i] + sbuf[3 * N + i];
}

// ---- prep: rows scaled by 1/lengthscale + squared norms ----
__global__ void prep_kernel(const float* __restrict__ tx, const float* __restrict__ xx,
                            const float* __restrict__ ls,
                            float* __restrict__ As, float* __restrict__ an,
                            float* __restrict__ Bs, float* __restrict__ bn) {
  int i = blockIdx.x * 256 + threadIdx.x;
  if (i < N_TRAIN) {
    float s = 0.f;
    #pragma unroll
    for (int d = 0; d < DIM; ++d) {
      float v = tx[(size_t)i * DIM + d] / ls[d];
      As[(size_t)i * DIM + d] = v; s += v * v;
    }
    an[i] = s;
  } else if (i < N_TRAIN + N_TEST) {
    int j = i - N_TRAIN;
    float s = 0.f;
    #pragma unroll
    for (int d = 0; d < DIM; ++d) {
      float v = xx[(size_t)j * DIM + d] / ls[d];
      Bs[(size_t)j * DIM + d] = v; s += v * v;
    }
    bn[j] = s;
  }
}

// ---- kernel-matrix builder: thread owns ADJACENT cols (4B coalesced stores) ----
template <bool NOISE>
__global__ __launch_bounds__(256) void build_kernel(
    const float* __restrict__ RI, const float* __restrict__ nI,
    const float* __restrict__ RJ, const float* __restrict__ nJ,
    unsigned short* __restrict__ O1,
    const float* __restrict__ osc, const float* __restrict__ noi)
{
  __shared__ float aI[128 * DIM];
  __shared__ float sI[128];
  int t = threadIdx.x;
  int j0 = blockIdx.x * 512, i0 = blockIdx.y * 128;
  for (int e = t; e < 128 * DIM; e += 256) aI[e] = RI[(size_t)i0 * DIM + e];
  if (t < 128) sI[t] = nI[i0 + t];
  __syncthreads();

  int ja = j0 + 2 * t, jb = ja + 1;
  f32x4 aj0[4], aj1[4];
  const f32x4* RJa = (const f32x4*)(RJ + (size_t)ja * DIM);
  const f32x4* RJb = (const f32x4*)(RJ + (size_t)jb * DIM);
  #pragma unroll
  for (int q = 0; q < 4; ++q) { aj0[q] = RJa[q]; aj1[q] = RJb[q]; }
  float nja = nJ[ja], njb = nJ[jb];
  float s = osc[0], sn = noi[0];

  for (int ic = 0; ic < 128; ic += 2) {
    f32x4 rv[2][4];
    #pragma unroll
    for (int r = 0; r < 2; ++r)
      #pragma unroll
      for (int q = 0; q < 4; ++q)
        rv[r][q] = *(const f32x4*)&aI[(ic + r) * DIM + q * 4];
    #pragma unroll
    for (int r = 0; r < 2; ++r) {
      int i = ic + r;
      float d0 = 0.f, d1 = 0.f;
      #pragma unroll
      for (int q = 0; q < 4; ++q) {
        f32x4 ai = rv[r][q];
        d0 += ai[0]*aj0[q][0] + ai[1]*aj0[q][1] + ai[2]*aj0[q][2] + ai[3]*aj0[q][3];
        d1 += ai[0]*aj1[q][0] + ai[1]*aj1[q][1] + ai[2]*aj1[q][2] + ai[3]*aj1[q][3];
      }
      float d2a = fmaxf(sI[i] + nja - 2.f * d0, 0.f);
      float d2b = fmaxf(sI[i] + njb - 2.f * d1, 0.f);
      float va = s * __expf(-0.5f * d2a);
      float vb = s * __expf(-0.5f * d2b);
      if (NOISE && (i0 + i == ja)) va += sn;
      if (NOISE && (i0 + i == jb)) vb += sn;
      unsigned pack = (unsigned)f2bf(va) | ((unsigned)f2bf(vb) << 16);
      *(unsigned*)&O1[(size_t)(i0 + i) * KDIM + ja] = pack;
    }
  }
}

// ============  256x256 8-phase pipelined MFMA GEMM (counted vmcnt)  ============
// Q[M][8192] = P[M][8192] * Khat^T. 512 thr (2M x 4N waves), per-wave 128x64.
// LDS [2 buf][2 half][128 rows x 64 bf16] for A and B = 128 KB.
// Swizzle: byte ^= ((row&7)<<4) within 128B rows (both sides, rule #21).

__device__ __forceinline__ void stage_h(const char* gtile, int kbyte,
                                        char* ldsdst, int tid, int wave) {
  #pragma unroll
  for (int q = 0; q < 2; ++q) {
    int o = q * 8192 + tid * 16;
    int r = o >> 7;
    int c = (o & 127) ^ ((r & 7) << 4);
    gl_lds16(gtile + (size_t)r * (KDIM * 2) + kbyte + c,
             ldsdst + q * 8192 + wave * 1024);   // wave-uniform dest, HW adds lane*16
  }
}

template <int FINAL>
__global__ __launch_bounds__(512, 1) void gemm256(
    const unsigned short* __restrict__ A,   // p (Rb for it0, else Pb) [M][KDIM]
    const unsigned short* __restrict__ Bm,  // Khat [8192][KDIM] bf16
    unsigned short* __restrict__ Cq,        // Q [M][8192] bf16
    int gy, float* __restrict__ pq)
{
  __shared__ char Ab[2][2][16384];   // [buf][half][128x64 bf16] = 64 KB
  __shared__ char Bb[2][2][16384];   // 64 KB
  const int tid = threadIdx.x, lane = tid & 63, wave = tid >> 6;
  const int wm = wave >> 2, wn = wave & 3;          // 2M x 4N
  const int nwg = gridDim.x, orig = blockIdx.x;
  const int wgid = (orig & 7) * (nwg >> 3) + (orig >> 3);   // XCD-chunked
  const int bx = wgid / gy, by = wgid % gy;
  const size_t HALF = (size_t)128 * KDIM * 2;

  const char* bA = (const char*)(A  + (size_t)(by * 256) * KDIM);
  const char* bB = (const char*)(Bm + (size_t)(bx * 256) * KDIM);

  // fragment LDS byte offsets within a 16KB half
  const int ar = wm * 64 + (lane & 15);
  const int br = wn * 32 + (lane & 15);
  const int hi = (lane >> 4) * 16;
  int aoff[4][2], boff[2][2];
  #pragma unroll
  for (int mf = 0; mf < 4; ++mf)
    #pragma unroll
    for (int kk = 0; kk < 2; ++kk)
      aoff[mf][kk] = (ar + mf * 16) * 128 + ((hi + kk * 64) ^ ((ar & 7) << 4));
  #pragma unroll
  for (int nf = 0; nf < 2; ++nf)
    #pragma unroll
    for (int kk = 0; kk < 2; ++kk)
      boff[nf][kk] = (br + nf * 16) * 128 + ((hi + kk * 64) ^ ((br & 7) << 4));

  f32x4 acc[2][2][4][2] = {};   // [mh][nh][mf][nf]
  bf16x8 aR[4][2], bR[2][2][2]; // aR[mf][kk], bR[nh][nf][kk]

#define BAR() __builtin_amdgcn_s_barrier()
#define PRIO1 __builtin_amdgcn_s_setprio(1)
#define PRIO0 __builtin_amdgcn_s_setprio(0)
#define FENCE8() asm volatile("s_waitcnt vmcnt(8)" ::: "memory")
#define FENCE6() asm volatile("s_waitcnt vmcnt(6)" ::: "memory")
#define FENCE0() asm volatile("s_waitcnt vmcnt(0)" ::: "memory")
#define STAGE_A(buf, mh, kb) stage_h(bA + ((mh) ? HALF : 0), kb, &Ab[buf][mh][0], tid, wave)
#define STAGE_B(buf, mh, kb) stage_h(bB + ((mh) ? HALF : 0), kb, &Bb[buf][mh][0], tid, wave)
#define LOAD_A(buf, mh)                                                        \
  { _Pragma("unroll") for (int mf = 0; mf < 4; ++mf)                           \
      _Pragma("unroll") for (int kk = 0; kk < 2; ++kk)                         \
        aR[mf][kk] = *(const bf16x8*)(&Ab[buf][mh][0] + aoff[mf][kk]); }
#define LOAD_B(buf, nh)                                                        \
  { _Pragma("unroll") for (int nf = 0; nf < 2; ++nf)                           \
      _Pragma("unroll") for (int kk = 0; kk < 2; ++kk)                         \
        bR[nh][nf][kk] = *(const bf16x8*)(&Bb[buf][nh][0] + boff[nf][kk]); }
#define MFMA16(mh, nh)                                                         \
  { _Pragma("unroll") for (int kk = 0; kk < 2; ++kk)                           \
      _Pragma("unroll") for (int mf = 0; mf < 4; ++mf)                         \
        _Pragma("unroll") for (int nf = 0; nf < 2; ++nf)                       \
          acc[mh][nh][mf][nf] = __builtin_amdgcn_mfma_f32_16x16x32_bf16(       \
              aR[mf][kk], bR[nh][nf][kk], acc[mh][nh][mf][nf], 0, 0, 0); }

  // prologue: tiles 0 (buf0) and 1 (buf1); order matters for the FIFO ledger
  STAGE_A(0, 0, 0);   STAGE_B(0, 0, 0);   STAGE_B(0, 1, 0);   STAGE_A(0, 1, 0);
  STAGE_A(1, 0, 128); STAGE_B(1, 0, 128); STAGE_B(1, 1, 128); STAGE_A(1, 1, 128);
  FENCE6();            // completes tile0 fully + A0(1); leaves B0,B1,A1(1) in flight
  BAR();

  for (int t = 0; t < NT; t += 2) {
    const bool g = (t + 2 < NT);
    const int kb2 = (t + 2) * 128, kb3 = (t + 3) * 128;
    // ph1: tile t quad(0,0) — no stage
    LOAD_A(0, 0); LOAD_B(0, 0);
    BAR(); PRIO1; MFMA16(0, 0); PRIO0; BAR();
    // ph2: quad(0,1); stage A0(t+2) [A0(t) consumed in ph1]
    if (g) STAGE_A(0, 0, kb2);
    LOAD_B(0, 1);
    BAR(); PRIO1; MFMA16(0, 1); PRIO0; BAR();
    // ph3: quad(1,0); stage B0(t+2) [B0(t) consumed ph1]
    if (g) STAGE_B(0, 0, kb2);
    LOAD_A(0, 1);
    BAR(); PRIO1; MFMA16(1, 0); PRIO0; BAR();
    // ph4: quad(1,1); stage B1(t+2)+A1(t+2) [consumed ph2/ph3]; fence -> tile t+1 ready
    if (g) { STAGE_B(0, 1, kb2); STAGE_A(0, 1, kb2); }
    BAR(); PRIO1; MFMA16(1, 1); PRIO0;
    if (g) { FENCE8(); } else { FENCE0(); }
    BAR();
    // ph5: tile t+1 quad(0,0) — no stage
    LOAD_A(1, 0); LOAD_B(1, 0);
    BAR(); PRIO1; MFMA16(0, 0); PRIO0; BAR();
    // ph6: quad(0,1); stage A0(t+3)
    if (g) STAGE_A(1, 0, kb3);
    LOAD_B(1, 1);
    BAR(); PRIO1; MFMA16(0, 1); PRIO0; BAR();
    // ph7: quad(1,0); stage B0(t+3)
    if (g) STAGE_B(1, 0, kb3);
    LOAD_A(1, 1);
    BAR(); PRIO1; MFMA16(1, 0); PRIO0; BAR();
    // ph8: quad(1,1); stage B1(t+3)+A1(t+3); fence -> tile t+2 fully done + A0(t+3)
    if (g) { STAGE_B(1, 1, kb3); STAGE_A(1, 1, kb3); }
    BAR(); PRIO1; MFMA16(1, 1); PRIO0;
    if (g) { FENCE6(); }
    BAR();
  }

  const int bm = by * 256, bn = bx * 256;
  if (!FINAL) {
    // C/D mapping (verified): col = lane&15, row = (lane>>4)*4 + reg
    #pragma unroll
    for (int mh = 0; mh < 2; ++mh)
      #pragma unroll
      for (int nh = 0; nh < 2; ++nh)
        #pragma unroll
        for (int mf = 0; mf < 4; ++mf)
          #pragma unroll
          for (int nf = 0; nf < 2; ++nf) {
            int row = bm + mh * 128 + wm * 64 + mf * 16 + (lane >> 4) * 4;
            int col = bn + nh * 128 + wn * 32 + nf * 16 + (lane & 15);
            #pragma unroll
            for (int rg = 0; rg < 4; ++rg)
              Cq[(size_t)(row + rg) * KDIM + col] = f2bf(acc[mh][nh][mf][nf][rg]);
          }
  } else {
    // final iteration: only pAp. pq[row] += sum_col P[row][col]*Q[row][col]
    #pragma unroll
    for (int mh = 0; mh < 2; ++mh)
      #pragma unroll
      for (int mf = 0; mf < 4; ++mf)
        #pragma unroll
        for (int rg = 0; rg < 4; ++rg) {
          int row = bm + mh * 128 + wm * 64 + mf * 16 + (lane >> 4) * 4 + rg;
          float v = 0.f;
          #pragma unroll
          for (int nh = 0; nh < 2; ++nh)
            #pragma unroll
            for (int nf = 0; nf < 2; ++nf) {
              int col = bn + nh * 128 + wn * 32 + nf * 16 + (lane & 15);
              v += acc[mh][nh][mf][nf][rg] * bf2f(A[(size_t)row * KDIM + col]);
            }
          v += __shfl_xor(v, 1); v += __shfl_xor(v, 2);
          v += __shfl_xor(v, 4); v += __shfl_xor(v, 8);
          if ((lane & 15) == 0) atomicAdd(&pq[row], v);
        }
  }
#undef MFMA16
#undef LOAD_B
#undef LOAD_A
#undef STAGE_B
#undef STAGE_A
#undef FENCE0
#undef FENCE6
#undef FENCE8
#undef PRIO0
#undef PRIO1
#undef BAR
}

// ---- CG step: single reduction (recurrence), fused R'/P' update ----
// scal[c*8]: {rr, yp, yr, mean, bx}
template <bool FIRST>
__global__ __launch_bounds__(256) void cg_step(
    const unsigned short* __restrict__ Q, unsigned short* __restrict__ R,
    unsigned short* __restrict__ P, const float* __restrict__ y,
    float* __restrict__ scal, float* __restrict__ pq)
{
  __shared__ float sbuf[24];
  int c = blockIdx.x, t = threadIdx.x;
  size_t base = (size_t)c * KDIM;

  bf16x8 q8[4], r8[4], p8[4];
  #pragma unroll
  for (int k = 0; k < 4; ++k) q8[k] = *(const bf16x8*)&Q[base + k * 2048 + t * 8];
  #pragma unroll
  for (int k = 0; k < 4; ++k) r8[k] = *(const bf16x8*)&R[base + k * 2048 + t * 8];
  if (FIRST) {
    #pragma unroll
    for (int k = 0; k < 4; ++k) p8[k] = r8[k];
  } else {
    #pragma unroll
    for (int k = 0; k < 4; ++k) p8[k] = *(const bf16x8*)&P[base + k * 2048 + t * 8];
  }

  // all dots in one pass: v = {p.q, r.q, q.q, y.q, r.r, y.r} (4,5 used on FIRST)
  float v[6] = {0.f, 0.f, 0.f, 0.f, 0.f, 0.f};
  #pragma unroll
  for (int k = 0; k < 4; ++k) {
    int j = k * 2048 + t * 8;
    f32x4 ya = *(const f32x4*)&y[j];
    f32x4 yb = *(const f32x4*)&y[j + 4];
    #pragma unroll
    for (int e = 0; e < 8; ++e) {
      float qv = bf2f((unsigned short)q8[k][e]);
      float rv = bf2f((unsigned short)r8[k][e]);
      float pv = FIRST ? rv : bf2f((unsigned short)p8[k][e]);
      float yv = (e < 4) ? ya[e] : yb[e - 4];
      v[0] += pv * qv; v[1] += rv * qv; v[2] += qv * qv; v[3] += yv * qv;
      if (FIRST) { v[4] += rv * rv; v[5] += yv * rv; }
    }
  }
  block_reduceN<6>(v, sbuf);

  float rr, yp, yr, mean, bx;
  if (FIRST) {
    rr = v[4]; yp = v[5]; yr = v[5]; mean = 0.f; bx = 0.f;
  } else {
    rr = scal[c*8+0]; yp = scal[c*8+1]; yr = scal[c*8+2];
    mean = scal[c*8+3]; bx = scal[c*8+4];
  }
  float alpha = rr / fmaxf(v[0], 1e-30f);
  mean += alpha * yp;
  bx   += alpha * rr;
  float rrn = fmaxf(rr - 2.f * alpha * v[1] + alpha * alpha * v[2], 0.f);
  float yrn = yr - alpha * v[3];
  float beta = rrn / fmaxf(rr, 1e-30f);
  float ypn  = yrn + beta * yp;

  // fused update: r' = r - alpha*q (write) ; p' = r'(rounded) + beta*p (write)
  #pragma unroll
  for (int k = 0; k < 4; ++k) {
    int j = k * 2048 + t * 8;
    bf16x8 wr, wp;
    #pragma unroll
    for (int e = 0; e < 8; ++e) {
      float rn = bf2f((unsigned short)r8[k][e]) -
                 alpha * bf2f((unsigned short)q8[k][e]);
      unsigned short hb = f2bf(rn);
      wr[e] = (short)hb;
      wp[e] = (short)f2bf(bf2f(hb) + beta * bf2f((unsigned short)p8[k][e]));
    }
    *(bf16x8*)&R[base + j] = wr;
    *(bf16x8*)&P[base + j] = wp;
  }
  if (t == 0) {
    scal[c*8+0] = rrn; scal[c*8+1] = ypn; scal[c*8+2] = yrn;
    scal[c*8+3] = mean; scal[c*8+4] = bx;
    pq[c] = 0.f;   // zero for the final gemm's atomics
  }
}

// ---- final outputs from pq (pAp of last iteration) + scal ----
__global__ void final_out(const float* __restrict__ pq, const float* __restrict__ scal,
                          const float* __restrict__ osc, const float* __restrict__ noi,
                          float* __restrict__ out, int c0, int C)
{
  int c = blockIdx.x * 256 + threadIdx.x;
  if (c >= C) return;
  float rr = scal[c*8+0], yp = scal[c*8+1];
  float mean = scal[c*8+3], bx = scal[c*8+4];
  float alpha = rr / fmaxf(pq[c], 1e-30f);
  mean += alpha * yp;
  bx   += alpha * rr;
  out[c0 + c] = mean;
  out[N_TEST + c0 + c] = osc[0] + noi[0] - bx;
}

extern "C" void kernel_launch(void* const* d_in, const int* in_sizes, int n_in,
                              void* d_out, int out_size, void* d_ws, size_t ws_size,
                              hipStream_t stream) {
  const float* tx = (const float*)d_in[0];
  const float* ty = (const float*)d_in[1];
  const float* xx = (const float*)d_in[2];
  const float* os = (const float*)d_in[3];
  const float* ls = (const float*)d_in[4];
  const float* ns = (const float*)d_in[5];
  float* out = (float*)d_out;
  (void)in_sizes; (void)n_in; (void)out_size;

  auto pad = [](size_t x) { return (x + 255) & ~(size_t)255; };
  size_t fixed = pad((size_t)N_TRAIN * KDIM * 2)
               + pad((size_t)N_TRAIN * DIM * 4) + pad((size_t)N_TRAIN * 4)
               + pad((size_t)N_TEST * DIM * 4) + pad((size_t)N_TEST * 4);
  int C = 4096;
  while (C > 256) {
    size_t tot = fixed + 3 * pad((size_t)C * KDIM * 2)
               + pad((size_t)C * 32) + pad((size_t)C * 4);
    if (tot <= ws_size) break;
    C >>= 1;
  }

  char* w = (char*)d_ws;
  auto alloc = [&](size_t bytes) { char* p = w; w += ((bytes + 255) & ~(size_t)255); return p; };
  unsigned short* Kb = (unsigned short*)alloc((size_t)N_TRAIN * KDIM * 2);
  float* As = (float*)alloc((size_t)N_TRAIN * DIM * 4);
  float* an = (float*)alloc((size_t)N_TRAIN * 4);
  float* Bs = (float*)alloc((size_t)N_TEST * DIM * 4);
  float* bn = (float*)alloc((size_t)N_TEST * 4);
  unsigned short* Rb = (unsigned short*)alloc((size_t)C * KDIM * 2);
  unsigned short* Pb = (unsigned short*)alloc((size_t)C * KDIM * 2);
  unsigned short* Qb = (unsigned short*)alloc((size_t)C * KDIM * 2);
  float* scal = (float*)alloc((size_t)C * 32);
  float* pq   = (float*)alloc((size_t)C * 4);

  prep_kernel<<<48, 256, 0, stream>>>(tx, xx, ls, As, an, Bs, bn);

  build_kernel<true><<<dim3(KDIM / 512, N_TRAIN / 128), 256, 0, stream>>>(
      As, an, As, an, Kb, os, ns);

  for (int c0 = 0; c0 < N_TEST; c0 += C) {
    build_kernel<false><<<dim3(KDIM / 512, C / 128), 256, 0, stream>>>(
        Bs + (size_t)c0 * DIM, bn + c0, As, an, Rb, os, ns);
    int gy = C / 256;
    dim3 gg(32 * gy);
    int scb = (C + 255) / 256;
    for (int it = 0; it < CG_ITERS; ++it) {
      const unsigned short* Ain = (it == 0) ? Rb : Pb;
      int fin = (it == CG_ITERS - 1) ? 1 : 0;
      if (!fin) {
        gemm256<0><<<gg, 512, 0, stream>>>(Ain, Kb, Qb, gy, pq);
        if (it == 0)
          cg_step<true><<<C, 256, 0, stream>>>(Qb, Rb, Pb, ty, scal, pq);
        else
          cg_step<false><<<C, 256, 0, stream>>>(Qb, Rb, Pb, ty, scal, pq);
      } else {
        gemm256<1><<<gg, 512, 0, stream>>>(Ain, Kb, Qb, gy, pq);
        final_out<<<scb, 256, 0, stream>>>(pq, scal, os, ns, out, c0, C);
      }
    }
  }
}